// Round 1
// 111.685 us; speedup vs baseline: 1.0588x; 1.0588x over previous
//
#include <hip/hip_runtime.h>
#include <hip/hip_fp16.h>
#include <math.h>

// CTC loss forward, SINGLE fused kernel v3: producer-consumer PIPELINED.
// One block of 1024 threads (16 waves) per batch element; B=256 = 256 CUs.
//
// v2 lesson (rocprof): kernel ~35 us = prep (~14 us, HBM-bound) then chain
// (~20 us, 1 wave/CU, serial recurrence) run back-to-back behind a
// __syncthreads. The chain's chunk c only needs LDS chunk c, so v3 overlaps:
//   - waves 1..15 = producers, round-robin chunk order (round r, wave pw
//     produces chunk 15r+pw), so chunks complete in consumption order.
//   - wave 0 = dedicated chain consumer; per-round LDS counters (ds_add after
//     s_waitcnt lgkmcnt(0)) gate its chunk prefetch. Producers never wait.
// Chain math identical to v2 (absmax = 1 bf16 ulp) except the per-step
// re-association nO = pE*dv + pO*(skf*dv) + aO*dv, which moves aO*dv and
// skf*dv off the serial critical path (DPP+fma+fma instead of
// DPP+fma+add+mul).
// B=256, T=512, C=128 (blank=127), L=64, S=129.

constexpr int Cc = 128;
constexpr int Tt = 512;
constexpr int Ll = 64;
constexpr int NCH = Tt / 8;                 // 64 chunks of 8 timesteps
constexpr int NPW = 15;                     // producer waves (wave 1..15)
constexpr int NR  = (NCH + NPW - 1) / NPW;  // 5 rounds
constexpr float INV_LN2 = 1.4426950408889634f;
constexpr float LN2_F   = 0.6931471805599453f;

__device__ __forceinline__ float fexp2(float x) { return __builtin_amdgcn_exp2f(x); }
__device__ __forceinline__ float flog2(float x) { return __builtin_amdgcn_logf(x); }

template<int CTRL, bool BC>
__device__ __forceinline__ float dppf(float old, float x) {
    return __int_as_float(__builtin_amdgcn_update_dpp(
        __float_as_int(old), __float_as_int(x), CTRL, 0xF, 0xF, BC));
}
// lane i <- lane i-1 across whole wave; lane 0 <- fill. (silicon-proven r3-r7)
__device__ __forceinline__ float wshr1(float x, float fill) { return dppf<0x138, false>(fill, x); }

__device__ __forceinline__ float rlf(float v, int lane) {
    return __int_as_float(__builtin_amdgcn_readlane(__float_as_int(v), lane));
}
// Row-local (16-lane) reduce; lanes 15/31/47/63 hold row results. (proven r6/r7)
__device__ __forceinline__ float rowsum(float e) {
    e += dppf<0x111, true>(0.f, e);
    e += dppf<0x112, true>(0.f, e);
    e += dppf<0x114, true>(0.f, e);
    e += dppf<0x118, true>(0.f, e);
    return e;
}
__device__ __forceinline__ float rowmax(float m) {   // m >= 0 (0-fill identity)
    m = fmaxf(m, dppf<0x111, true>(0.f, m));
    m = fmaxf(m, dppf<0x112, true>(0.f, m));
    m = fmaxf(m, dppf<0x114, true>(0.f, m));
    m = fmaxf(m, dppf<0x118, true>(0.f, m));
    return m;
}
__device__ __forceinline__ float allmax(float m) {
    m = rowmax(m);
    return fmaxf(fmaxf(rlf(m, 15), rlf(m, 31)), fmaxf(rlf(m, 47), rlf(m, 63)));
}
__device__ __forceinline__ float bperm_f(int srclane, float v) {
    return __int_as_float(__builtin_amdgcn_ds_bpermute(srclane << 2, __float_as_int(v)));
}
__device__ __forceinline__ float gather4(float4 v, int srclane, int csel) {
    const float gx = bperm_f(srclane, v.x), gy = bperm_f(srclane, v.y);
    const float gz = bperm_f(srclane, v.z), gw = bperm_f(srclane, v.w);
    const float lo = (csel & 1) ? gy : gx;
    const float hi = (csel & 1) ? gw : gz;
    return (csel & 2) ? hi : lo;
}

// 8 chain steps + zero-lag renorm on a packed fp16 chunk (proven r7; v3:
// re-associated so the serial path is DPP -> fma -> fma).
template<bool GUARD>
__device__ __forceinline__ void do_chunk(uint4 raw, int t0, int inlen, float skf,
                                         float& aO, float& aE, float& r0, float& Rtot)
{
    float dv[8];
    {
        const __half2 h0 = *reinterpret_cast<const __half2*>(&raw.x);
        const __half2 h1 = *reinterpret_cast<const __half2*>(&raw.y);
        const __half2 h2 = *reinterpret_cast<const __half2*>(&raw.z);
        const __half2 h3 = *reinterpret_cast<const __half2*>(&raw.w);
        dv[0] = __low2float(h0); dv[1] = __high2float(h0);
        dv[2] = __low2float(h1); dv[3] = __high2float(h1);
        dv[4] = __low2float(h2); dv[5] = __high2float(h2);
        dv[6] = __low2float(h3); dv[7] = __high2float(h3);
    }
    float sd[8];
#pragma unroll
    for (int j = 0; j < 8; ++j) sd[j] = skf * dv[j];   // off critical path
#pragma unroll
    for (int j = 0; j < 8; ++j) {
        if (!GUARD || (t0 + j < inlen)) {
            const float ad = aO * dv[j];        // starts as soon as aO settles
            const float pE = wshr1(aE, r0);     // beta[2l]; lane0: state0
            const float pO = wshr1(aO, 0.0f);   // beta[2l-1]
            const float nO = fmaf(pE, dv[j], fmaf(pO, sd[j], ad));
            aE += aO;
            aO = nO;
        }
    }
    const float M_ = allmax(fmaxf(fmaxf(aO, aE), r0));
    int R_ = (int)(__float_as_uint(M_) >> 23) - 127;
    R_ = (R_ < 0) ? 0 : ((R_ > 126) ? 126 : R_);
    const float sc = __uint_as_float((unsigned)(127 - R_) << 23);
    aO = fminf(aO * sc, 4.0f);
    aE = fminf(aE * sc, 4.0f);
    r0 = fminf(r0 * sc, 4.0f);
    Rtot += (float)R_;
}

__global__ __launch_bounds__(1024, 1) void ctc_fused3_kernel(
    const int* __restrict__ y_true,      // [B, 64]
    const float* __restrict__ y_pred,    // [B, T, C]
    const int* __restrict__ in_len,      // [B]
    const int* __restrict__ lab_len,     // [B]
    float* __restrict__ out)             // [B]
{
    __shared__ __half w_lds[NCH][64][8];  // [chunk][lane][t&7], 64 KB
    __shared__ float  ps[NPW];            // per-producer-wave blank partial sums (log2)
    __shared__ int    rctr[NR];           // per-round completion counters

    const int b   = blockIdx.x;
    const int tid = threadIdx.x;
    const int w   = tid >> 6;             // wave 0..15
    const int l   = tid & 63;

    if (tid < NR) rctr[tid] = 0;
    __syncthreads();

    int inlen = in_len[b]; if (inlen < 1) inlen = 1; if (inlen > Tt) inlen = Tt;
    int LLv   = lab_len[b]; if (LLv < 1) LLv = 1; if (LLv > Ll) LLv = Ll;

    const int lab = y_true[b * Ll + l] & 127;
    const float* rowbase = y_pred + (size_t)b * Tt * Cc;

    if (w != 0) {
        // ---------------- producers: waves 1..15, round-robin chunk order -------
        const int pw   = w - 1;
        const int half = l >> 5, li = l & 31;
        const int srcA = lab >> 2;        // lane (in low half) holding class `lab`
        const int csel = lab & 3;
        const bool live = (l < LLv);      // r6 fix: dead lattice lanes -> w = 0

        float acc = 0.0f;                 // sum of lp2_blank over rows < inlen

        float4 vb[4];
#pragma unroll
        for (int j = 0; j < 4; ++j)
            vb[j] = ((const float4*)(rowbase + (size_t)(pw * 8 + 2 * j + half) * Cc))[li];

        for (int c = pw, r = 0; c < NCH; c += NPW, ++r) {
            const int cn = c + NPW;       // next chunk for this wave (prefetch)
#pragma unroll
            for (int j = 0; j < 4; ++j) {
                const float4 v = vb[j];
                if (cn < NCH)
                    vb[j] = ((const float4*)(rowbase + (size_t)(cn * 8 + 2 * j + half) * Cc))[li];

                const int rA = c * 8 + 2 * j;
                const int rB = rA + 1;

                // lse (log2) for both rows: row_shr partial sums + readlane combine
                float e = (fexp2(v.x * INV_LN2) + fexp2(v.y * INV_LN2))
                        + (fexp2(v.z * INV_LN2) + fexp2(v.w * INV_LN2));
                e = rowsum(e);
                const float sA = rlf(e, 15) + rlf(e, 31);
                const float sB = rlf(e, 47) + rlf(e, 63);
                const float lsA = flog2(sA), lsB = flog2(sB);
                const float blA = rlf(v.w, 31);      // blank logit, row A (uniform)
                const float blB = rlf(v.w, 63);      // blank logit, row B

                // blank partial sum (uniform across lanes)
                const float lpbA = fmaf(blA, INV_LN2, -lsA);
                const float lpbB = fmaf(blB, INV_LN2, -lsB);
                acc += ((rA < inlen) ? lpbA : 0.0f) + ((rB < inlen) ? lpbB : 0.0f);

                // per-lane label weights -> LDS chunk layout
                const float xA = gather4(v, srcA, csel);
                const float xB = gather4(v, srcA + 32, csel);
                float wA = fminf(fmaxf(fexp2((xA - blA) * INV_LN2), 6.1e-5f), 8192.0f);
                float wB = fminf(fmaxf(fexp2((xB - blB) * INV_LN2), 6.1e-5f), 8192.0f);
                wA = live ? wA : 0.0f;
                wB = live ? wB : 0.0f;
                const unsigned packed =
                      (unsigned)__half_as_ushort(__float2half(wA))
                    | ((unsigned)__half_as_ushort(__float2half(wB)) << 16);
                *(unsigned*)&w_lds[c][l][2 * j] = packed;   // 2j even: 4B aligned
            }
            // last chunk for this wave: publish blank partial BEFORE the flag
            if (cn >= NCH && l == 0) ps[pw] = acc;
            // drain this wave's ds_writes, then bump the round counter
            asm volatile("s_waitcnt lgkmcnt(0)" ::: "memory");
            if (l == 0) atomicAdd(&rctr[r], 1);
        }
        return;   // producers never wait on the consumer -> no deadlock
    }

    // ---------------- consumer: wave 0, 512-step linear recurrence -------------
    const int labp = __shfl_up(lab, 1, 64);
    const float skf = ((l >= 1) && (lab != labp)) ? 1.0f : 0.0f;

    float aO = 0.0f, aE = 0.0f, r0 = 1.0f, Rtot = 0.0f;
    const int nchunks = (inlen + 7) >> 3;       // >= 32

    volatile int* vctr = rctr;
    int ready = 0, rr = 0;
    // ensure chunks 0..cneed are published (fast path: scalar compare only)
    auto wait_upto = [&](int cneed) {
        while (ready <= cneed) {
            const int rem  = NCH - rr * NPW;
            const int need = rem < NPW ? rem : NPW;
            if (vctr[rr] >= need) { ready += need; ++rr; }
            else __builtin_amdgcn_s_sleep(1);
        }
        asm volatile("" ::: "memory");          // acquire: no hoisting of data reads
    };

    wait_upto(0);
    uint4 A = *(const uint4*)&w_lds[0][l][0];
    for (int c = 0; c < nchunks; ++c) {
        uint4 Bv = A;
        if (c + 1 < nchunks) {                  // prefetch next chunk once ready
            wait_upto(c + 1);
            Bv = *(const uint4*)&w_lds[c + 1][l][0];
        }
        const int t0 = c * 8;
        if (t0 + 8 <= inlen) do_chunk<false>(A, t0, inlen, skf, aO, aE, r0, Rtot);
        else                 do_chunk<true >(A, t0, inlen, skf, aO, aE, r0, Rtot);
        A = Bv;
    }

    // wait for ALL rounds (every producer past its final flag => ps[] complete)
    while (rr < NR) {
        const int rem  = NCH - rr * NPW;
        const int need = rem < NPW ? rem : NPW;
        if (vctr[rr] >= need) ++rr;
        else __builtin_amdgcn_s_sleep(1);
    }
    asm volatile("" ::: "memory");

    // cum_blank (log2): sum the 15 per-wave partials (uniform)
    float cum_b = 0.0f;
#pragma unroll
    for (int q = 0; q < NPW; ++q) cum_b += ps[q];

    // readout: states 2*LL (aE) and 2*LL-1 (aO) live on lane LL-1
    const float aEr = __shfl(aE, LLv - 1, 64);
    const float aOr = __shfl(aO, LLv - 1, 64);
    if (l == 0)
        out[b] = -LN2_F * (flog2(fmaxf(aEr + aOr, 1e-37f)) + Rtot + cum_b);
}

extern "C" void kernel_launch(void* const* d_in, const int* in_sizes, int n_in,
                              void* d_out, int out_size, void* d_ws, size_t ws_size,
                              hipStream_t stream) {
    const int*   y_true  = (const int*)d_in[0];    // [256,64]
    const float* y_pred  = (const float*)d_in[1];  // [256,512,128]
    const int*   in_len  = (const int*)d_in[2];    // [256]
    const int*   lab_len = (const int*)d_in[3];    // [256]
    float*       out     = (float*)d_out;          // [256]
    (void)d_ws; (void)ws_size;

    ctc_fused3_kernel<<<256, 1024, 0, stream>>>(y_true, y_pred, in_len, lab_len, out);
}

// Round 2
// 111.669 us; speedup vs baseline: 1.0590x; 1.0001x over previous
//
#include <hip/hip_runtime.h>
#include <hip/hip_fp16.h>
#include <math.h>

// CTC loss forward, SINGLE fused kernel v4: pipelined producer-consumer
// (v3) + STRAIGHT-LINE producer round body.
// One block of 1024 threads (16 waves) per batch element; B=256 = 256 CUs.
//
// v3 lesson (A/B): overlap hid the whole chain (-6.5 us == chain length);
// kernel is now prep-bound at ~28.5 us while issue-bound arithmetic says
// ~5-12 us -> prep is LATENCY-bound. Cause: the conditional prefetch inside
// each unrolled j splits the round body into 4+ basic blocks, killing
// cross-j ILP (8 independent ~150-cycle chains can't overlap).
// v4: (a) prefetch chunk index CLAMPED (always-legal address) so the load is
// unconditional and the 4-j body is one basic block; (b) per-round log2
// fusion: acc += bsum*INV_LN2 - log2(prod of masked s), 1 log2/round instead
// of 8 (dead rows contribute s=1); product of <=8 row-sums (~400 each) stays
// << f32 max. Everything else (chain math, flags, readout) identical to v3.
// B=256, T=512, C=128 (blank=127), L=64, S=129.

constexpr int Cc = 128;
constexpr int Tt = 512;
constexpr int Ll = 64;
constexpr int NCH = Tt / 8;                 // 64 chunks of 8 timesteps
constexpr int NPW = 15;                     // producer waves (wave 1..15)
constexpr int NR  = (NCH + NPW - 1) / NPW;  // 5 rounds
constexpr float INV_LN2 = 1.4426950408889634f;
constexpr float LN2_F   = 0.6931471805599453f;

__device__ __forceinline__ float fexp2(float x) { return __builtin_amdgcn_exp2f(x); }
__device__ __forceinline__ float flog2(float x) { return __builtin_amdgcn_logf(x); }

template<int CTRL, bool BC>
__device__ __forceinline__ float dppf(float old, float x) {
    return __int_as_float(__builtin_amdgcn_update_dpp(
        __float_as_int(old), __float_as_int(x), CTRL, 0xF, 0xF, BC));
}
// lane i <- lane i-1 across whole wave; lane 0 <- fill. (silicon-proven r3-r7)
__device__ __forceinline__ float wshr1(float x, float fill) { return dppf<0x138, false>(fill, x); }

__device__ __forceinline__ float rlf(float v, int lane) {
    return __int_as_float(__builtin_amdgcn_readlane(__float_as_int(v), lane));
}
// Row-local (16-lane) reduce; lanes 15/31/47/63 hold row results. (proven r6/r7)
__device__ __forceinline__ float rowsum(float e) {
    e += dppf<0x111, true>(0.f, e);
    e += dppf<0x112, true>(0.f, e);
    e += dppf<0x114, true>(0.f, e);
    e += dppf<0x118, true>(0.f, e);
    return e;
}
__device__ __forceinline__ float rowmax(float m) {   // m >= 0 (0-fill identity)
    m = fmaxf(m, dppf<0x111, true>(0.f, m));
    m = fmaxf(m, dppf<0x112, true>(0.f, m));
    m = fmaxf(m, dppf<0x114, true>(0.f, m));
    m = fmaxf(m, dppf<0x118, true>(0.f, m));
    return m;
}
__device__ __forceinline__ float allmax(float m) {
    m = rowmax(m);
    return fmaxf(fmaxf(rlf(m, 15), rlf(m, 31)), fmaxf(rlf(m, 47), rlf(m, 63)));
}
__device__ __forceinline__ float bperm_f(int srclane, float v) {
    return __int_as_float(__builtin_amdgcn_ds_bpermute(srclane << 2, __float_as_int(v)));
}
__device__ __forceinline__ float gather4(float4 v, int srclane, int csel) {
    const float gx = bperm_f(srclane, v.x), gy = bperm_f(srclane, v.y);
    const float gz = bperm_f(srclane, v.z), gw = bperm_f(srclane, v.w);
    const float lo = (csel & 1) ? gy : gx;
    const float hi = (csel & 1) ? gw : gz;
    return (csel & 2) ? hi : lo;
}

// 8 chain steps + zero-lag renorm on a packed fp16 chunk (proven r7; v3:
// re-associated so the serial path is DPP -> fma -> fma).
template<bool GUARD>
__device__ __forceinline__ void do_chunk(uint4 raw, int t0, int inlen, float skf,
                                         float& aO, float& aE, float& r0, float& Rtot)
{
    float dv[8];
    {
        const __half2 h0 = *reinterpret_cast<const __half2*>(&raw.x);
        const __half2 h1 = *reinterpret_cast<const __half2*>(&raw.y);
        const __half2 h2 = *reinterpret_cast<const __half2*>(&raw.z);
        const __half2 h3 = *reinterpret_cast<const __half2*>(&raw.w);
        dv[0] = __low2float(h0); dv[1] = __high2float(h0);
        dv[2] = __low2float(h1); dv[3] = __high2float(h1);
        dv[4] = __low2float(h2); dv[5] = __high2float(h2);
        dv[6] = __low2float(h3); dv[7] = __high2float(h3);
    }
    float sd[8];
#pragma unroll
    for (int j = 0; j < 8; ++j) sd[j] = skf * dv[j];   // off critical path
#pragma unroll
    for (int j = 0; j < 8; ++j) {
        if (!GUARD || (t0 + j < inlen)) {
            const float ad = aO * dv[j];        // starts as soon as aO settles
            const float pE = wshr1(aE, r0);     // beta[2l]; lane0: state0
            const float pO = wshr1(aO, 0.0f);   // beta[2l-1]
            const float nO = fmaf(pE, dv[j], fmaf(pO, sd[j], ad));
            aE += aO;
            aO = nO;
        }
    }
    const float M_ = allmax(fmaxf(fmaxf(aO, aE), r0));
    int R_ = (int)(__float_as_uint(M_) >> 23) - 127;
    R_ = (R_ < 0) ? 0 : ((R_ > 126) ? 126 : R_);
    const float sc = __uint_as_float((unsigned)(127 - R_) << 23);
    aO = fminf(aO * sc, 4.0f);
    aE = fminf(aE * sc, 4.0f);
    r0 = fminf(r0 * sc, 4.0f);
    Rtot += (float)R_;
}

__global__ __launch_bounds__(1024, 1) void ctc_fused4_kernel(
    const int* __restrict__ y_true,      // [B, 64]
    const float* __restrict__ y_pred,    // [B, T, C]
    const int* __restrict__ in_len,      // [B]
    const int* __restrict__ lab_len,     // [B]
    float* __restrict__ out)             // [B]
{
    __shared__ __half w_lds[NCH][64][8];  // [chunk][lane][t&7], 64 KB
    __shared__ float  ps[NPW];            // per-producer-wave blank partial sums (log2)
    __shared__ int    rctr[NR];           // per-round completion counters

    const int b   = blockIdx.x;
    const int tid = threadIdx.x;
    const int w   = tid >> 6;             // wave 0..15
    const int l   = tid & 63;

    if (tid < NR) rctr[tid] = 0;
    __syncthreads();

    int inlen = in_len[b]; if (inlen < 1) inlen = 1; if (inlen > Tt) inlen = Tt;
    int LLv   = lab_len[b]; if (LLv < 1) LLv = 1; if (LLv > Ll) LLv = Ll;

    const int lab = y_true[b * Ll + l] & 127;
    const float* rowbase = y_pred + (size_t)b * Tt * Cc;

    if (w != 0) {
        // ---------------- producers: waves 1..15, round-robin chunk order -------
        const int pw   = w - 1;
        const int half = l >> 5, li = l & 31;
        const int srcA = lab >> 2;        // lane (in low half) holding class `lab`
        const int csel = lab & 3;
        const bool live = (l < LLv);      // r6 fix: dead lattice lanes -> w = 0

        float acc = 0.0f;                 // sum of lp2_blank over rows < inlen

        float4 vb[4];
#pragma unroll
        for (int j = 0; j < 4; ++j)
            vb[j] = ((const float4*)(rowbase + (size_t)(pw * 8 + 2 * j + half) * Cc))[li];

        int r = 0;
        for (int c = pw; c < NCH; c += NPW, ++r) {
            // clamped (always-legal) prefetch index -> UNCONDITIONAL loads ->
            // the whole 4-j body is one basic block (cross-j ILP).
            const int cn = (c + NPW < NCH) ? (c + NPW) : (NCH - 1);
            float prod = 1.0f, bsum = 0.0f;
#pragma unroll
            for (int j = 0; j < 4; ++j) {
                const float4 v = vb[j];
                vb[j] = ((const float4*)(rowbase + (size_t)(cn * 8 + 2 * j + half) * Cc))[li];

                const int rA = c * 8 + 2 * j;
                const int rB = rA + 1;

                // row-pair softmax denominators (log2 deferred to round tail)
                float e = (fexp2(v.x * INV_LN2) + fexp2(v.y * INV_LN2))
                        + (fexp2(v.z * INV_LN2) + fexp2(v.w * INV_LN2));
                e = rowsum(e);
                const float sA = rlf(e, 15) + rlf(e, 31);
                const float sB = rlf(e, 47) + rlf(e, 63);
                const float blA = rlf(v.w, 31);      // blank logit, row A (uniform)
                const float blB = rlf(v.w, 63);      // blank logit, row B

                const bool okA = rA < inlen, okB = rB < inlen;
                prod *= okB ? sA * sB : (okA ? sA : 1.0f);   // dead rows -> 1
                bsum += okB ? blA + blB : (okA ? blA : 0.0f);

                // per-lane label weights -> LDS chunk layout
                const float xA = gather4(v, srcA, csel);
                const float xB = gather4(v, srcA + 32, csel);
                float wA = fminf(fmaxf(fexp2((xA - blA) * INV_LN2), 6.1e-5f), 8192.0f);
                float wB = fminf(fmaxf(fexp2((xB - blB) * INV_LN2), 6.1e-5f), 8192.0f);
                wA = live ? wA : 0.0f;
                wB = live ? wB : 0.0f;
                const unsigned packed =
                      (unsigned)__half_as_ushort(__float2half(wA))
                    | ((unsigned)__half_as_ushort(__float2half(wB)) << 16);
                *(unsigned*)&w_lds[c][l][2 * j] = packed;   // 2j even: 4B aligned
            }
            // fold: acc += bsum*INV_LN2 - sum(log2 s) via single log2 of product
            acc = fmaf(bsum, INV_LN2, acc) - flog2(prod);
            // last chunk for this wave: publish blank partial BEFORE the flag
            if (c + NPW >= NCH && l == 0) ps[pw] = acc;
            // drain this wave's ds_writes, then bump the round counter
            asm volatile("s_waitcnt lgkmcnt(0)" ::: "memory");
            if (l == 0) atomicAdd(&rctr[r], 1);
        }
        return;   // producers never wait on the consumer -> no deadlock
    }

    // ---------------- consumer: wave 0, 512-step linear recurrence -------------
    const int labp = __shfl_up(lab, 1, 64);
    const float skf = ((l >= 1) && (lab != labp)) ? 1.0f : 0.0f;

    float aO = 0.0f, aE = 0.0f, r0 = 1.0f, Rtot = 0.0f;
    const int nchunks = (inlen + 7) >> 3;       // >= 32

    volatile int* vctr = rctr;
    int ready = 0, rr = 0;
    // ensure chunks 0..cneed are published (fast path: scalar compare only)
    auto wait_upto = [&](int cneed) {
        while (ready <= cneed) {
            const int rem  = NCH - rr * NPW;
            const int need = rem < NPW ? rem : NPW;
            if (vctr[rr] >= need) { ready += need; ++rr; }
            else __builtin_amdgcn_s_sleep(1);
        }
        asm volatile("" ::: "memory");          // acquire: no hoisting of data reads
    };

    wait_upto(0);
    uint4 A = *(const uint4*)&w_lds[0][l][0];
    for (int c = 0; c < nchunks; ++c) {
        uint4 Bv = A;
        if (c + 1 < nchunks) {                  // prefetch next chunk once ready
            wait_upto(c + 1);
            Bv = *(const uint4*)&w_lds[c + 1][l][0];
        }
        const int t0 = c * 8;
        if (t0 + 8 <= inlen) do_chunk<false>(A, t0, inlen, skf, aO, aE, r0, Rtot);
        else                 do_chunk<true >(A, t0, inlen, skf, aO, aE, r0, Rtot);
        A = Bv;
    }

    // wait for ALL rounds (every producer past its final flag => ps[] complete)
    while (rr < NR) {
        const int rem  = NCH - rr * NPW;
        const int need = rem < NPW ? rem : NPW;
        if (vctr[rr] >= need) ++rr;
        else __builtin_amdgcn_s_sleep(1);
    }
    asm volatile("" ::: "memory");

    // cum_blank (log2): sum the 15 per-wave partials (uniform)
    float cum_b = 0.0f;
#pragma unroll
    for (int q = 0; q < NPW; ++q) cum_b += ps[q];

    // readout: states 2*LL (aE) and 2*LL-1 (aO) live on lane LL-1
    const float aEr = __shfl(aE, LLv - 1, 64);
    const float aOr = __shfl(aO, LLv - 1, 64);
    if (l == 0)
        out[b] = -LN2_F * (flog2(fmaxf(aEr + aOr, 1e-37f)) + Rtot + cum_b);
}

extern "C" void kernel_launch(void* const* d_in, const int* in_sizes, int n_in,
                              void* d_out, int out_size, void* d_ws, size_t ws_size,
                              hipStream_t stream) {
    const int*   y_true  = (const int*)d_in[0];    // [256,64]
    const float* y_pred  = (const float*)d_in[1];  // [256,512,128]
    const int*   in_len  = (const int*)d_in[2];    // [256]
    const int*   lab_len = (const int*)d_in[3];    // [256]
    float*       out     = (float*)d_out;          // [256]
    (void)d_ws; (void)ws_size;

    ctc_fused4_kernel<<<256, 1024, 0, stream>>>(y_true, y_pred, in_len, lab_len, out);
}